// Round 8
// baseline (247.678 us; speedup 1.0000x reference)
//
#include <hip/hip_runtime.h>

#define D_MODEL 1024
#define NHEAD 16
#define LN_EPS 1e-5f
#define CHUNK 32
#define S_LEN 4096
#define NCH (S_LEN / CHUNK)   // 128

typedef unsigned short u16;
typedef __attribute__((ext_vector_type(8))) short short8;
typedef __attribute__((ext_vector_type(8))) unsigned short u16x8;
typedef __attribute__((ext_vector_type(4))) float f32x4;

__device__ __forceinline__ u16 f2b(float f) {
  unsigned u = __builtin_bit_cast(unsigned, f);
  u += 0x7FFFu + ((u >> 16) & 1u);   // RNE
  return (u16)(u >> 16);
}
__device__ __forceinline__ float b2f(u16 s) {
  return __builtin_bit_cast(float, ((unsigned)s) << 16);
}

// ---------------- fused fp32->bf16 convert (x + 4 weights) + lam ----------------
// One balanced grid-stride loop over nx4 + 4*nw4 float4 items (all pow2 -> shifts).
__device__ __forceinline__ ushort4 cvt4(float4 f) {
  ushort4 o; o.x = f2b(f.x); o.y = f2b(f.y); o.z = f2b(f.z); o.w = f2b(f.w);
  return o;
}
__global__ __launch_bounds__(256) void cvt_all(
    const float4* __restrict__ x,  const float4* __restrict__ wq,
    const float4* __restrict__ wv, const float4* __restrict__ wg,
    const float4* __restrict__ wo, ushort4* __restrict__ xb,
    ushort4* __restrict__ wqvg, ushort4* __restrict__ wob,
    const float* __restrict__ beta, float* __restrict__ lam,
    int nx4, int nw4) {
  int i = blockIdx.x * blockDim.x + threadIdx.x;
  int stride = gridDim.x * blockDim.x;
  if (blockIdx.x == 0 && threadIdx.x < NHEAD) {
    float l = 1.f / (1.f + __expf(-beta[threadIdx.x]));
    lam[threadIdx.x] = l;                  // lambda
    lam[NHEAD + threadIdx.x] = __log2f(l); // log2(lambda)
  }
  const int total = nx4 + 4 * nw4;
  for (int j = i; j < total; j += stride) {
    float4 f; ushort4* dst;
    if (j < nx4) { f = x[j]; dst = xb + j; }
    else {
      int k = j - nx4;
      int w = k / nw4, o = k - w * nw4;    // nw4 = 2^18 -> shifts
      const float4* s = (w == 0) ? wq : (w == 1) ? wv : (w == 2) ? wg : wo;
      f = s[o];
      dst = (w < 3) ? (wqvg + (size_t)w * nw4 + o) : (wob + o);
    }
    *dst = cvt4(f);
  }
}

// ============ 256x256 tile, BK=64, 2-dbuf pipelined GEMM (frag-lead, r6) ============
// + XCD-aware block swizzle (T1; nwg % 8 == 0 for both launches -> bijective).
// + CARRY epilogue (r7): per-32-row-chunk EMA totals for v-columns from fp32 acc.

__device__ __forceinline__ void glds16(const u16* g, const u16* l) {
  __builtin_amdgcn_global_load_lds(
      (const __attribute__((address_space(1))) unsigned*)g,
      (__attribute__((address_space(3))) unsigned*)l, 16, 0, 0);
}

#define BAR() asm volatile("s_barrier" ::: "memory")
#define SB0() __builtin_amdgcn_sched_barrier(0)

template <typename OutT, bool CARRY>
__global__ __launch_bounds__(512, 2) void gemm256(const u16* __restrict__ X,
                                                  const u16* __restrict__ W,
                                                  OutT* __restrict__ Out,
                                                  float* __restrict__ carry,
                                                  const float* __restrict__ lamlog,
                                                  int M, int N, int K) {
  __shared__ u16 sm[8][8192];   // unit = d*4 + ab*2 + h ; 16 KB each
  const int tid = threadIdx.x;
  const int lane = tid & 63;
  const int wave = tid >> 6;              // 0..7
  const int ln15 = lane & 15, lh = lane >> 4;
  const int wr = wave >> 2, wc = wave & 3;

  // ---- XCD swizzle: contiguous work chunks per XCD ----
  const int lin = blockIdx.y * gridDim.x + blockIdx.x;
  const int cpx = (gridDim.x * gridDim.y) >> 3;
  const int sw = (lin & 7) * cpx + (lin >> 3);
  const int bm = (sw % gridDim.x) * 256;
  const int bn = (sw / gridDim.x) * 256;
  const int NT = K >> 6;                  // K-tiles of 64 (>= 3)

  // ---- staging source (pre-swizzled global 16B-chunk within 128B row) ----
  const int srow = tid >> 3;                              // 0..63
  const int scol = ((tid & 7) ^ (srow & 7)) << 3;         // u16 col
  const u16* Asrc = X + (size_t)(bm + srow) * K + scol;
  const u16* Bsrc = W + (size_t)(bn + srow) * K + scol;
  const int ldsw = wave * 512;            // wave's u16 offset inside a unit

#define STAGE(u, h, tile, src)                                          \
  { const u16* _g = (src) + (size_t)((h) * 128) * K + (tile) * 64;      \
    glds16(_g,                  &sm[u][ldsw]);                          \
    glds16(_g + (size_t)64 * K, &sm[u][ldsw + 4096]); }

  // ---- ds_read bases (swizzled) ----
  const char* smb = (const char*)&sm[0][0];
  const char* Ard = smb + wr * 16384 + ln15 * 128;
  const char* Brd = smb + (2 + (wc >> 1)) * 16384 + ((wc & 1) * 64 + ln15) * 128;
  const int swz0 = ((lh ^ (ln15 & 7)) << 4);              // ks=0 chunk
  const int swz1 = (((4 + lh) ^ (ln15 & 7)) << 4);        // ks=1 chunk

#define RD_A(DB, MM, S) (*(const short8*)(Ard + (DB) + (MM) * 2048 + (S)))
#define RD_B(DB, NN, S) (*(const short8*)(Brd + (DB) + (NN) * 2048 + (S)))

  f32x4 acc[8][4];
  f32x4 zero = {0.f, 0.f, 0.f, 0.f};
  #pragma unroll
  for (int m = 0; m < 8; ++m)
    #pragma unroll
    for (int n = 0; n < 4; ++n) acc[m][n] = zero;

  short8 a[8][2], b[4][2];

#define MFMA_Q(M0, N0)                                                        \
  SB0();                                                                      \
  __builtin_amdgcn_s_setprio(1);                                              \
  _Pragma("unroll")                                                           \
  for (int m = (M0); m < (M0) + 4; ++m)                                       \
    _Pragma("unroll")                                                         \
    for (int n = (N0); n < (N0) + 2; ++n) {                                   \
      acc[m][n] = __builtin_amdgcn_mfma_f32_16x16x32_bf16(a[m][0], b[n][0], acc[m][n], 0, 0, 0); \
      acc[m][n] = __builtin_amdgcn_mfma_f32_16x16x32_bf16(a[m][1], b[n][1], acc[m][n], 0, 0, 0); \
    }                                                                         \
  __builtin_amdgcn_s_setprio(0);                                              \
  SB0();

  // ---- prologue ----
  STAGE(0, 0, 0, Asrc); STAGE(1, 1, 0, Asrc);
  STAGE(2, 0, 0, Bsrc); STAGE(3, 1, 0, Bsrc);
  STAGE(4, 0, 1, Asrc); STAGE(5, 1, 1, Asrc);
  asm volatile("s_waitcnt vmcnt(4)" ::: "memory");   // tile0 landed; A(1) flying
  BAR();
  #pragma unroll
  for (int m = 0; m < 4; ++m) { a[m][0] = RD_A(0, m, swz0); a[m][1] = RD_A(0, m, swz1); }
  #pragma unroll
  for (int n = 0; n < 4; ++n) { b[n][0] = RD_B(0, n, swz0); b[n][1] = RD_B(0, n, swz1); }

  for (int t = 0; t < NT; ++t) {
    const int d = t & 1;
    const int db = d * 65536;
    const int odb = (d ^ 1) * 65536;
    const int od = (d ^ 1) * 4;
    const int sd = d * 4;
    const int tB = (t + 1 < NT) ? t + 1 : NT - 1;
    const int tA = (t + 2 < NT) ? t + 2 : NT - 1;

    // ---- ph1: read a45(t); stage Bh0(t+1); MFMA Q1 = A0 x B0 ----
    a[4][0] = RD_A(db, 4, swz0); a[4][1] = RD_A(db, 4, swz1);
    a[5][0] = RD_A(db, 5, swz0); a[5][1] = RD_A(db, 5, swz1);
    STAGE(od + 2, 0, tB, Bsrc);
    MFMA_Q(0, 0)

    // ---- ph2: read a67(t); stage Bh1(t+1); MFMA Q2 = A0 x B1 ----
    a[6][0] = RD_A(db, 6, swz0); a[6][1] = RD_A(db, 6, swz1);
    a[7][0] = RD_A(db, 7, swz0); a[7][1] = RD_A(db, 7, swz1);
    STAGE(od + 3, 1, tB, Bsrc);
    MFMA_Q(0, 2)
    asm volatile("s_waitcnt vmcnt(4)" ::: "memory");
    BAR();

    // ---- ph3: read a03(t+1); MFMA Q3 = A1 x B1; stage Ah0(t+2) ----
    #pragma unroll
    for (int m = 0; m < 4; ++m) { a[m][0] = RD_A(odb, m, swz0); a[m][1] = RD_A(odb, m, swz1); }
    MFMA_Q(4, 2)
    STAGE(sd + 0, 0, tA, Asrc);
    asm volatile("s_waitcnt vmcnt(2)" ::: "memory");   // B(t+1) landed; Ah0(t+2) flying
    BAR();

    // ---- ph4: read b23(t+1); MFMA Q4 = A1 x B0; read b01(t+1); stage Ah1(t+2) ----
    b[2][0] = RD_B(odb, 2, swz0); b[2][1] = RD_B(odb, 2, swz1);
    b[3][0] = RD_B(odb, 3, swz0); b[3][1] = RD_B(odb, 3, swz1);
    MFMA_Q(4, 0)
    b[0][0] = RD_B(odb, 0, swz0); b[0][1] = RD_B(odb, 0, swz1);
    b[1][0] = RD_B(odb, 1, swz0); b[1][1] = RD_B(odb, 1, swz1);
    STAGE(sd + 1, 1, tA, Asrc);
  }
#undef STAGE
#undef RD_A
#undef RD_B
#undef MFMA_Q

  // ---- epilogue: C write ----
  #pragma unroll
  for (int m = 0; m < 8; ++m)
    #pragma unroll
    for (int n = 0; n < 4; ++n)
      #pragma unroll
      for (int r = 0; r < 4; ++r) {
        int row = bm + wr * 128 + m * 16 + lh * 4 + r;   // C/D: row=(lane>>4)*4+reg
        int col = bn + wc * 64 + n * 16 + ln15;          //      col=lane&15
        float vv = acc[m][n][r];
        if constexpr (sizeof(OutT) == 2) Out[(size_t)row * N + col] = f2b(vv);
        else                             Out[(size_t)row * N + col] = vv;
      }

  // ---- epilogue 2: per-chunk EMA totals for v-columns ----
  if constexpr (CARRY) {
    if (bn >= 1024 && bn < 2048) {
      const int bidx = bm >> 12;                         // batch (4096 rows each)
      const int chunkbase = ((bm & 4095) >> 5) + wr * 4; // 32-row chunks
      const int colbase = (bn - 1024) + wc * 64;         // v-col base (head-uniform)
      const float l2h = lamlog[colbase >> 6];
      float wgt[2][4];
      #pragma unroll
      for (int mo = 0; mo < 2; ++mo)
        #pragma unroll
        for (int r = 0; r < 4; ++r)
          wgt[mo][r] = exp2f(l2h * (float)(31 - (mo * 16 + lh * 4 + r)));
      #pragma unroll
      for (int mq = 0; mq < 4; ++mq) {      // chunk = chunkbase + mq
        #pragma unroll
        for (int n = 0; n < 4; ++n) {
          float part = 0.f;
          #pragma unroll
          for (int mo = 0; mo < 2; ++mo)
            #pragma unroll
            for (int r = 0; r < 4; ++r)
              part += wgt[mo][r] * acc[mq * 2 + mo][n][r];
          part += __shfl_down(part, 16);
          part += __shfl_down(part, 32);
          if (lh == 0)
            carry[(size_t)(bidx * NCH + chunkbase + mq) * D_MODEL +
                  colbase + n * 16 + ln15] = part;
        }
      }
    }
  }
}

// ---------------- carry prefix: c_j = lambda^CHUNK * c_{j-1} + total_j ----------------
__global__ void scan_carry(float* __restrict__ carry, const float* __restrict__ lam,
                           int B, int nch) {
  int idx = blockIdx.x * blockDim.x + threadIdx.x;
  if (idx >= B * D_MODEL) return;
  int b = idx >> 10, col = idx & (D_MODEL - 1);
  float lC = exp2f(lam[NHEAD + (col >> 6)] * (float)CHUNK);
  float c = 0.f;
  #pragma unroll 4
  for (int j = 0; j < nch; ++j) {
    size_t a = ((size_t)(b * nch + j)) * D_MODEL + col;
    c = lC * c + carry[a];
    carry[a] = c;
  }
}

// ---------------- fused local-scan + q*state + LayerNorm + SiLU gate ----------------
// One 128-thread block (2 waves) per (b,chunk); 8 cols/thread, ushort8 (16B)
// loads; per-row: in-thread 8-col partial + 6-level shfl + 2-wave LDS combine
// (one __syncthreads per row, parity slots); next-row loads prefetched.
__global__ __launch_bounds__(128) void scan_ln(const u16* __restrict__ qvg,
    const float* __restrict__ carry, const float* __restrict__ lam,
    const float* __restrict__ gamma, const float* __restrict__ lbeta,
    u16* __restrict__ yout, int S, int nch, int ld) {
  const int bj = blockIdx.x;               // b*nch + j
  const int b = bj / nch, j = bj - b * nch;
  const int tid = threadIdx.x;             // 0..127
  const int col0 = tid * 8;
  const float l = lam[col0 >> 6];

  float gm[8], bt[8];
  #pragma unroll
  for (int i = 0; i < 8; ++i) { gm[i] = gamma[col0 + i]; bt[i] = lbeta[col0 + i]; }

  float cp[8] = {0.f, 0.f, 0.f, 0.f, 0.f, 0.f, 0.f, 0.f};
  if (j > 0) {
    const float* cb = carry + (size_t)(bj - 1) * D_MODEL + col0;
    #pragma unroll
    for (int i = 0; i < 8; ++i) cp[i] = cb[i];
  }
  float s[8] = {0.f, 0.f, 0.f, 0.f, 0.f, 0.f, 0.f, 0.f};
  float p = l;                              // lambda^{t+1}
  const size_t row0 = (size_t)b * S + (size_t)j * CHUNK;
  const u16* base = qvg + row0 * ld + col0;

  u16x8 qu = *(const u16x8*)(base);
  u16x8 vu = *(const u16x8*)(base + D_MODEL);
  u16x8 gu = *(const u16x8*)(base + 2 * D_MODEL);

  __shared__ float red[2][2][2];            // [parity][{sum,sumsq}][wave]
  const int ln = tid & 63, wv = tid >> 6;

  for (int t = 0; t < CHUNK; ++t) {
    u16x8 qn, vn, gn;
    if (t + 1 < CHUNK) {
      const u16* nb = base + (size_t)(t + 1) * ld;
      qn = *(const u16x8*)(nb);
      vn = *(const u16x8*)(nb + D_MODEL);
      gn = *(const u16x8*)(nb + 2 * D_MODEL);
    }
    float y[8];
    float sum = 0.f, sumsq = 0.f;
    #pragma unroll
    for (int i = 0; i < 8; ++i) {
      s[i] = l * s[i] + b2f(vu[i]);
      float st = s[i] + p * cp[i];
      float yy = b2f(qu[i]) * st;
      y[i] = yy; sum += yy; sumsq += yy * yy;
    }
    #pragma unroll
    for (int off = 32; off > 0; off >>= 1) {
      sum += __shfl_down(sum, off);
      sumsq += __shfl_down(sumsq, off);
    }
    const int par = t & 1;
    if (ln == 0) { red[par][0][wv] = sum; red[par][1][wv] = sumsq; }
    __syncthreads();
    sum = red[par][0][0] + red[par][0][1];
    sumsq = red[par][1][0] + red[par][1][1];
    float mu = sum * (1.f / 1024.f);
    float var = sumsq * (1.f / 1024.f) - mu * mu;
    float rstd = rsqrtf(var + LN_EPS);

    u16x8 o;
    #pragma unroll
    for (int i = 0; i < 8; ++i) {
      float g = b2f(gu[i]);
      float oo = ((y[i] - mu) * rstd * gm[i] + bt[i]) * (g / (1.f + __expf(-g)));
      o[i] = f2b(oo);
    }
    *(u16x8*)(yout + (row0 + t) * D_MODEL + col0) = o;

    if (t + 1 < CHUNK) { qu = qn; vu = vn; gu = gn; }
    p *= l;
  }
}

extern "C" void kernel_launch(void* const* d_in, const int* in_sizes, int n_in,
                              void* d_out, int out_size, void* d_ws, size_t ws_size,
                              hipStream_t stream) {
  const float* x     = (const float*)d_in[0];
  const float* Wq    = (const float*)d_in[1];
  const float* Wv    = (const float*)d_in[2];
  const float* Wo    = (const float*)d_in[3];
  const float* Wg    = (const float*)d_in[4];
  const float* beta  = (const float*)d_in[5];
  const float* gamma = (const float*)d_in[6];
  const float* lbeta = (const float*)d_in[7];
  float* out = (float*)d_out;

  const int BS = in_sizes[0] / D_MODEL;     // 16384
  const int S = S_LEN;                       // 4096
  const int B = BS / S;                      // 4
  const int nch = NCH;                       // 128
  const size_t nx = (size_t)BS * D_MODEL;
  const size_t nw = (size_t)D_MODEL * D_MODEL;
  const int N3 = 3 * D_MODEL;                // 3072

  char* w = (char*)d_ws;
  u16* xb   = (u16*)w;  w += nx * 2;
  u16* wqvg = (u16*)w;  w += 3 * nw * 2;     // packed [Wq;Wv;Wg] rows
  u16* wob  = (u16*)w;  w += nw * 2;
  u16* qvg  = (u16*)w;  w += (size_t)BS * N3 * 2;   // packed [q|v|g] per row
  u16* yb   = (u16*)w;  w += nx * 2;
  float* carry = (float*)w;  w += (size_t)B * nch * D_MODEL * 4;
  float* lam = (float*)w;

  cvt_all<<<2048, 256, 0, stream>>>((const float4*)x, (const float4*)Wq,
      (const float4*)Wv, (const float4*)Wg, (const float4*)Wo,
      (ushort4*)xb, (ushort4*)wqvg, (ushort4*)wob, beta, lam,
      (int)(nx / 4), (int)(nw / 4));

  dim3 g1(BS / 256, N3 / 256);      // 64 x 12 = 768 (%8==0)
  gemm256<u16, true><<<g1, 512, 0, stream>>>(xb, wqvg, qvg, carry, lam + NHEAD,
                                             BS, N3, D_MODEL);

  scan_carry<<<(B * D_MODEL + 255) / 256, 256, 0, stream>>>(carry, lam, B, nch);
  scan_ln<<<B * nch, 128, 0, stream>>>(qvg, carry, lam, gamma, lbeta, yb, S, nch, N3);

  dim3 g2(BS / 256, D_MODEL / 256); // 64 x 4 = 256 (%8==0)
  gemm256<float, false><<<g2, 512, 0, stream>>>(yb, wob, out, nullptr, nullptr,
                                                BS, D_MODEL, D_MODEL);
}

// Round 9
// 236.320 us; speedup vs baseline: 1.0481x; 1.0481x over previous
//
#include <hip/hip_runtime.h>

#define D_MODEL 1024
#define NHEAD 16
#define LN_EPS 1e-5f
#define CHUNK 32
#define S_LEN 4096
#define NCH (S_LEN / CHUNK)   // 128

typedef unsigned short u16;
typedef __attribute__((ext_vector_type(8))) short short8;
typedef __attribute__((ext_vector_type(8))) unsigned short u16x8;
typedef __attribute__((ext_vector_type(4))) float f32x4;

__device__ __forceinline__ u16 f2b(float f) {
  unsigned u = __builtin_bit_cast(unsigned, f);
  u += 0x7FFFu + ((u >> 16) & 1u);   // RNE
  return (u16)(u >> 16);
}
__device__ __forceinline__ float b2f(u16 s) {
  return __builtin_bit_cast(float, ((unsigned)s) << 16);
}

// ---------------- fused fp32->bf16 convert (x + 4 weights) + lam ----------------
// One balanced grid-stride loop over nx4 + 4*nw4 float4 items (all pow2 -> shifts).
__device__ __forceinline__ ushort4 cvt4(float4 f) {
  ushort4 o; o.x = f2b(f.x); o.y = f2b(f.y); o.z = f2b(f.z); o.w = f2b(f.w);
  return o;
}
__global__ __launch_bounds__(256) void cvt_all(
    const float4* __restrict__ x,  const float4* __restrict__ wq,
    const float4* __restrict__ wv, const float4* __restrict__ wg,
    const float4* __restrict__ wo, ushort4* __restrict__ xb,
    ushort4* __restrict__ wqvg, ushort4* __restrict__ wob,
    const float* __restrict__ beta, float* __restrict__ lam,
    int nx4, int nw4) {
  int i = blockIdx.x * blockDim.x + threadIdx.x;
  int stride = gridDim.x * blockDim.x;
  if (blockIdx.x == 0 && threadIdx.x < NHEAD) {
    float l = 1.f / (1.f + __expf(-beta[threadIdx.x]));
    lam[threadIdx.x] = l;                  // lambda
    lam[NHEAD + threadIdx.x] = __log2f(l); // log2(lambda)
  }
  const int total = nx4 + 4 * nw4;
  for (int j = i; j < total; j += stride) {
    float4 f; ushort4* dst;
    if (j < nx4) { f = x[j]; dst = xb + j; }
    else {
      int k = j - nx4;
      int w = k / nw4, o = k - w * nw4;    // nw4 = 2^18 -> shifts
      const float4* s = (w == 0) ? wq : (w == 1) ? wv : (w == 2) ? wg : wo;
      f = s[o];
      dst = (w < 3) ? (wqvg + (size_t)w * nw4 + o) : (wob + o);
    }
    *dst = cvt4(f);
  }
}

// ============ 256x256 tile, BK=64, 2-dbuf pipelined GEMM (frag-lead, r6) ============
// NO XCD swizzle: the natural bx-fastest dispatch already keeps all resident
// blocks on one B-panel per sweep (FETCH ~= compulsory 74MB); r8's chunked
// remap broke L3 A-stream reuse (FETCH 2.7x, -12us) — measured, reverted.
// + CARRY epilogue (r7): per-32-row-chunk EMA totals for v-columns from fp32 acc.

__device__ __forceinline__ void glds16(const u16* g, const u16* l) {
  __builtin_amdgcn_global_load_lds(
      (const __attribute__((address_space(1))) unsigned*)g,
      (__attribute__((address_space(3))) unsigned*)l, 16, 0, 0);
}

#define BAR() asm volatile("s_barrier" ::: "memory")
#define SB0() __builtin_amdgcn_sched_barrier(0)

template <typename OutT, bool CARRY>
__global__ __launch_bounds__(512, 2) void gemm256(const u16* __restrict__ X,
                                                  const u16* __restrict__ W,
                                                  OutT* __restrict__ Out,
                                                  float* __restrict__ carry,
                                                  const float* __restrict__ lamlog,
                                                  int M, int N, int K) {
  __shared__ u16 sm[8][8192];   // unit = d*4 + ab*2 + h ; 16 KB each
  const int tid = threadIdx.x;
  const int lane = tid & 63;
  const int wave = tid >> 6;              // 0..7
  const int ln15 = lane & 15, lh = lane >> 4;
  const int wr = wave >> 2, wc = wave & 3;
  const int bm = blockIdx.x * 256, bn = blockIdx.y * 256;
  const int NT = K >> 6;                  // K-tiles of 64 (>= 3)

  // ---- staging source (pre-swizzled global 16B-chunk within 128B row) ----
  const int srow = tid >> 3;                              // 0..63
  const int scol = ((tid & 7) ^ (srow & 7)) << 3;         // u16 col
  const u16* Asrc = X + (size_t)(bm + srow) * K + scol;
  const u16* Bsrc = W + (size_t)(bn + srow) * K + scol;
  const int ldsw = wave * 512;            // wave's u16 offset inside a unit

#define STAGE(u, h, tile, src)                                          \
  { const u16* _g = (src) + (size_t)((h) * 128) * K + (tile) * 64;      \
    glds16(_g,                  &sm[u][ldsw]);                          \
    glds16(_g + (size_t)64 * K, &sm[u][ldsw + 4096]); }

  // ---- ds_read bases (swizzled) ----
  const char* smb = (const char*)&sm[0][0];
  const char* Ard = smb + wr * 16384 + ln15 * 128;
  const char* Brd = smb + (2 + (wc >> 1)) * 16384 + ((wc & 1) * 64 + ln15) * 128;
  const int swz0 = ((lh ^ (ln15 & 7)) << 4);              // ks=0 chunk
  const int swz1 = (((4 + lh) ^ (ln15 & 7)) << 4);        // ks=1 chunk

#define RD_A(DB, MM, S) (*(const short8*)(Ard + (DB) + (MM) * 2048 + (S)))
#define RD_B(DB, NN, S) (*(const short8*)(Brd + (DB) + (NN) * 2048 + (S)))

  f32x4 acc[8][4];
  f32x4 zero = {0.f, 0.f, 0.f, 0.f};
  #pragma unroll
  for (int m = 0; m < 8; ++m)
    #pragma unroll
    for (int n = 0; n < 4; ++n) acc[m][n] = zero;

  short8 a[8][2], b[4][2];

#define MFMA_Q(M0, N0)                                                        \
  SB0();                                                                      \
  __builtin_amdgcn_s_setprio(1);                                              \
  _Pragma("unroll")                                                           \
  for (int m = (M0); m < (M0) + 4; ++m)                                       \
    _Pragma("unroll")                                                         \
    for (int n = (N0); n < (N0) + 2; ++n) {                                   \
      acc[m][n] = __builtin_amdgcn_mfma_f32_16x16x32_bf16(a[m][0], b[n][0], acc[m][n], 0, 0, 0); \
      acc[m][n] = __builtin_amdgcn_mfma_f32_16x16x32_bf16(a[m][1], b[n][1], acc[m][n], 0, 0, 0); \
    }                                                                         \
  __builtin_amdgcn_s_setprio(0);                                              \
  SB0();

  // ---- prologue ----
  STAGE(0, 0, 0, Asrc); STAGE(1, 1, 0, Asrc);
  STAGE(2, 0, 0, Bsrc); STAGE(3, 1, 0, Bsrc);
  STAGE(4, 0, 1, Asrc); STAGE(5, 1, 1, Asrc);
  asm volatile("s_waitcnt vmcnt(4)" ::: "memory");   // tile0 landed; A(1) flying
  BAR();
  #pragma unroll
  for (int m = 0; m < 4; ++m) { a[m][0] = RD_A(0, m, swz0); a[m][1] = RD_A(0, m, swz1); }
  #pragma unroll
  for (int n = 0; n < 4; ++n) { b[n][0] = RD_B(0, n, swz0); b[n][1] = RD_B(0, n, swz1); }

  for (int t = 0; t < NT; ++t) {
    const int d = t & 1;
    const int db = d * 65536;
    const int odb = (d ^ 1) * 65536;
    const int od = (d ^ 1) * 4;
    const int sd = d * 4;
    const int tB = (t + 1 < NT) ? t + 1 : NT - 1;
    const int tA = (t + 2 < NT) ? t + 2 : NT - 1;

    // ---- ph1: read a45(t); stage Bh0(t+1); MFMA Q1 = A0 x B0 ----
    a[4][0] = RD_A(db, 4, swz0); a[4][1] = RD_A(db, 4, swz1);
    a[5][0] = RD_A(db, 5, swz0); a[5][1] = RD_A(db, 5, swz1);
    STAGE(od + 2, 0, tB, Bsrc);
    MFMA_Q(0, 0)

    // ---- ph2: read a67(t); stage Bh1(t+1); MFMA Q2 = A0 x B1 ----
    a[6][0] = RD_A(db, 6, swz0); a[6][1] = RD_A(db, 6, swz1);
    a[7][0] = RD_A(db, 7, swz0); a[7][1] = RD_A(db, 7, swz1);
    STAGE(od + 3, 1, tB, Bsrc);
    MFMA_Q(0, 2)
    asm volatile("s_waitcnt vmcnt(4)" ::: "memory");
    BAR();

    // ---- ph3: read a03(t+1); MFMA Q3 = A1 x B1; stage Ah0(t+2) ----
    #pragma unroll
    for (int m = 0; m < 4; ++m) { a[m][0] = RD_A(odb, m, swz0); a[m][1] = RD_A(odb, m, swz1); }
    MFMA_Q(4, 2)
    STAGE(sd + 0, 0, tA, Asrc);
    asm volatile("s_waitcnt vmcnt(2)" ::: "memory");   // B(t+1) landed; Ah0(t+2) flying
    BAR();

    // ---- ph4: read b23(t+1); MFMA Q4 = A1 x B0; read b01(t+1); stage Ah1(t+2) ----
    b[2][0] = RD_B(odb, 2, swz0); b[2][1] = RD_B(odb, 2, swz1);
    b[3][0] = RD_B(odb, 3, swz0); b[3][1] = RD_B(odb, 3, swz1);
    MFMA_Q(4, 0)
    b[0][0] = RD_B(odb, 0, swz0); b[0][1] = RD_B(odb, 0, swz1);
    b[1][0] = RD_B(odb, 1, swz0); b[1][1] = RD_B(odb, 1, swz1);
    STAGE(sd + 1, 1, tA, Asrc);
  }
#undef STAGE
#undef RD_A
#undef RD_B
#undef MFMA_Q

  // ---- epilogue: C write ----
  #pragma unroll
  for (int m = 0; m < 8; ++m)
    #pragma unroll
    for (int n = 0; n < 4; ++n)
      #pragma unroll
      for (int r = 0; r < 4; ++r) {
        int row = bm + wr * 128 + m * 16 + lh * 4 + r;   // C/D: row=(lane>>4)*4+reg
        int col = bn + wc * 64 + n * 16 + ln15;          //      col=lane&15
        float vv = acc[m][n][r];
        if constexpr (sizeof(OutT) == 2) Out[(size_t)row * N + col] = f2b(vv);
        else                             Out[(size_t)row * N + col] = vv;
      }

  // ---- epilogue 2: per-chunk EMA totals for v-columns ----
  if constexpr (CARRY) {
    if (bn >= 1024 && bn < 2048) {
      const int bidx = bm >> 12;                         // batch (4096 rows each)
      const int chunkbase = ((bm & 4095) >> 5) + wr * 4; // 32-row chunks
      const int colbase = (bn - 1024) + wc * 64;         // v-col base (head-uniform)
      const float l2h = lamlog[colbase >> 6];
      float wgt[2][4];
      #pragma unroll
      for (int mo = 0; mo < 2; ++mo)
        #pragma unroll
        for (int r = 0; r < 4; ++r)
          wgt[mo][r] = exp2f(l2h * (float)(31 - (mo * 16 + lh * 4 + r)));
      #pragma unroll
      for (int mq = 0; mq < 4; ++mq) {      // chunk = chunkbase + mq
        #pragma unroll
        for (int n = 0; n < 4; ++n) {
          float part = 0.f;
          #pragma unroll
          for (int mo = 0; mo < 2; ++mo)
            #pragma unroll
            for (int r = 0; r < 4; ++r)
              part += wgt[mo][r] * acc[mq * 2 + mo][n][r];
          part += __shfl_down(part, 16);
          part += __shfl_down(part, 32);
          if (lh == 0)
            carry[(size_t)(bidx * NCH + chunkbase + mq) * D_MODEL +
                  colbase + n * 16 + ln15] = part;
        }
      }
    }
  }
}

// ---------------- carry prefix: c_j = lambda^CHUNK * c_{j-1} + total_j ----------------
__global__ void scan_carry(float* __restrict__ carry, const float* __restrict__ lam,
                           int B, int nch) {
  int idx = blockIdx.x * blockDim.x + threadIdx.x;
  if (idx >= B * D_MODEL) return;
  int b = idx >> 10, col = idx & (D_MODEL - 1);
  float lC = exp2f(lam[NHEAD + (col >> 6)] * (float)CHUNK);
  float c = 0.f;
  #pragma unroll 4
  for (int j = 0; j < nch; ++j) {
    size_t a = ((size_t)(b * nch + j)) * D_MODEL + col;
    c = lC * c + carry[a];
    carry[a] = c;
  }
}

// ---------------- fused local-scan + q*state + LayerNorm + SiLU gate ----------------
// One 128-thread block (2 waves) per (b,chunk); 8 cols/thread, ushort8 (16B)
// loads; per-row: in-thread 8-col partial + 6-level shfl + 2-wave LDS combine
// (one __syncthreads per row, parity slots); next-row loads prefetched.
__global__ __launch_bounds__(128) void scan_ln(const u16* __restrict__ qvg,
    const float* __restrict__ carry, const float* __restrict__ lam,
    const float* __restrict__ gamma, const float* __restrict__ lbeta,
    u16* __restrict__ yout, int S, int nch, int ld) {
  const int bj = blockIdx.x;               // b*nch + j
  const int b = bj / nch, j = bj - b * nch;
  const int tid = threadIdx.x;             // 0..127
  const int col0 = tid * 8;
  const float l = lam[col0 >> 6];

  float gm[8], bt[8];
  #pragma unroll
  for (int i = 0; i < 8; ++i) { gm[i] = gamma[col0 + i]; bt[i] = lbeta[col0 + i]; }

  float cp[8] = {0.f, 0.f, 0.f, 0.f, 0.f, 0.f, 0.f, 0.f};
  if (j > 0) {
    const float* cb = carry + (size_t)(bj - 1) * D_MODEL + col0;
    #pragma unroll
    for (int i = 0; i < 8; ++i) cp[i] = cb[i];
  }
  float s[8] = {0.f, 0.f, 0.f, 0.f, 0.f, 0.f, 0.f, 0.f};
  float p = l;                              // lambda^{t+1}
  const size_t row0 = (size_t)b * S + (size_t)j * CHUNK;
  const u16* base = qvg + row0 * ld + col0;

  u16x8 qu = *(const u16x8*)(base);
  u16x8 vu = *(const u16x8*)(base + D_MODEL);
  u16x8 gu = *(const u16x8*)(base + 2 * D_MODEL);

  __shared__ float red[2][2][2];            // [parity][{sum,sumsq}][wave]
  const int ln = tid & 63, wv = tid >> 6;

  for (int t = 0; t < CHUNK; ++t) {
    u16x8 qn, vn, gn;
    if (t + 1 < CHUNK) {
      const u16* nb = base + (size_t)(t + 1) * ld;
      qn = *(const u16x8*)(nb);
      vn = *(const u16x8*)(nb + D_MODEL);
      gn = *(const u16x8*)(nb + 2 * D_MODEL);
    }
    float y[8];
    float sum = 0.f, sumsq = 0.f;
    #pragma unroll
    for (int i = 0; i < 8; ++i) {
      s[i] = l * s[i] + b2f(vu[i]);
      float st = s[i] + p * cp[i];
      float yy = b2f(qu[i]) * st;
      y[i] = yy; sum += yy; sumsq += yy * yy;
    }
    #pragma unroll
    for (int off = 32; off > 0; off >>= 1) {
      sum += __shfl_down(sum, off);
      sumsq += __shfl_down(sumsq, off);
    }
    const int par = t & 1;
    if (ln == 0) { red[par][0][wv] = sum; red[par][1][wv] = sumsq; }
    __syncthreads();
    sum = red[par][0][0] + red[par][0][1];
    sumsq = red[par][1][0] + red[par][1][1];
    float mu = sum * (1.f / 1024.f);
    float var = sumsq * (1.f / 1024.f) - mu * mu;
    float rstd = rsqrtf(var + LN_EPS);

    u16x8 o;
    #pragma unroll
    for (int i = 0; i < 8; ++i) {
      float g = b2f(gu[i]);
      float oo = ((y[i] - mu) * rstd * gm[i] + bt[i]) * (g / (1.f + __expf(-g)));
      o[i] = f2b(oo);
    }
    *(u16x8*)(yout + (row0 + t) * D_MODEL + col0) = o;

    if (t + 1 < CHUNK) { qu = qn; vu = vn; gu = gn; }
    p *= l;
  }
}

extern "C" void kernel_launch(void* const* d_in, const int* in_sizes, int n_in,
                              void* d_out, int out_size, void* d_ws, size_t ws_size,
                              hipStream_t stream) {
  const float* x     = (const float*)d_in[0];
  const float* Wq    = (const float*)d_in[1];
  const float* Wv    = (const float*)d_in[2];
  const float* Wo    = (const float*)d_in[3];
  const float* Wg    = (const float*)d_in[4];
  const float* beta  = (const float*)d_in[5];
  const float* gamma = (const float*)d_in[6];
  const float* lbeta = (const float*)d_in[7];
  float* out = (float*)d_out;

  const int BS = in_sizes[0] / D_MODEL;     // 16384
  const int S = S_LEN;                       // 4096
  const int B = BS / S;                      // 4
  const int nch = NCH;                       // 128
  const size_t nx = (size_t)BS * D_MODEL;
  const size_t nw = (size_t)D_MODEL * D_MODEL;
  const int N3 = 3 * D_MODEL;                // 3072

  char* w = (char*)d_ws;
  u16* xb   = (u16*)w;  w += nx * 2;
  u16* wqvg = (u16*)w;  w += 3 * nw * 2;     // packed [Wq;Wv;Wg] rows
  u16* wob  = (u16*)w;  w += nw * 2;
  u16* qvg  = (u16*)w;  w += (size_t)BS * N3 * 2;   // packed [q|v|g] per row
  u16* yb   = (u16*)w;  w += nx * 2;
  float* carry = (float*)w;  w += (size_t)B * nch * D_MODEL * 4;
  float* lam = (float*)w;

  cvt_all<<<2048, 256, 0, stream>>>((const float4*)x, (const float4*)Wq,
      (const float4*)Wv, (const float4*)Wg, (const float4*)Wo,
      (ushort4*)xb, (ushort4*)wqvg, (ushort4*)wob, beta, lam,
      (int)(nx / 4), (int)(nw / 4));

  dim3 g1(BS / 256, N3 / 256);      // 64 x 12
  gemm256<u16, true><<<g1, 512, 0, stream>>>(xb, wqvg, qvg, carry, lam + NHEAD,
                                             BS, N3, D_MODEL);

  scan_carry<<<(B * D_MODEL + 255) / 256, 256, 0, stream>>>(carry, lam, B, nch);
  scan_ln<<<B * nch, 128, 0, stream>>>(qvg, carry, lam, gamma, lbeta, yb, S, nch, N3);

  dim3 g2(BS / 256, D_MODEL / 256); // 64 x 4
  gemm256<float, false><<<g2, 512, 0, stream>>>(yb, wob, out, nullptr, nullptr,
                                                BS, D_MODEL, D_MODEL);
}

// Round 10
// 228.115 us; speedup vs baseline: 1.0858x; 1.0360x over previous
//
#include <hip/hip_runtime.h>

#define D_MODEL 1024
#define NHEAD 16
#define LN_EPS 1e-5f
#define CHUNK 32
#define S_LEN 4096
#define NCH (S_LEN / CHUNK)   // 128

typedef unsigned short u16;
typedef __attribute__((ext_vector_type(8))) short short8;
typedef __attribute__((ext_vector_type(4))) float f32x4;

__device__ __forceinline__ u16 f2b(float f) {
  unsigned u = __builtin_bit_cast(unsigned, f);
  u += 0x7FFFu + ((u >> 16) & 1u);   // RNE
  return (u16)(u >> 16);
}
__device__ __forceinline__ float b2f(u16 s) {
  return __builtin_bit_cast(float, ((unsigned)s) << 16);
}
__device__ __forceinline__ void u4f(ushort4 u, float* f) {
  f[0] = b2f(u.x); f[1] = b2f(u.y); f[2] = b2f(u.z); f[3] = b2f(u.w);
}

// ---------------- fused fp32->bf16 convert (x + 4 weights) + lam (r6 version) ----------------
// Separate compile-time-strided loops; no runtime division (r8's balanced loop
// with k/nw4 runtime-div was a measured regression — reverted).
__device__ __forceinline__ ushort4 cvt4(float4 f) {
  ushort4 o; o.x = f2b(f.x); o.y = f2b(f.y); o.z = f2b(f.z); o.w = f2b(f.w);
  return o;
}
__global__ __launch_bounds__(256) void cvt_all(
    const float4* __restrict__ x,  const float4* __restrict__ wq,
    const float4* __restrict__ wv, const float4* __restrict__ wg,
    const float4* __restrict__ wo, ushort4* __restrict__ xb,
    ushort4* __restrict__ wqvg, ushort4* __restrict__ wob,
    const float* __restrict__ beta, float* __restrict__ lam,
    int nx4, int nw4) {
  int i = blockIdx.x * blockDim.x + threadIdx.x;
  int stride = gridDim.x * blockDim.x;
  if (blockIdx.x == 0 && threadIdx.x < NHEAD) {
    float l = 1.f / (1.f + __expf(-beta[threadIdx.x]));
    lam[threadIdx.x] = l;                  // lambda
    lam[NHEAD + threadIdx.x] = __log2f(l); // log2(lambda)
  }
  for (int j = i; j < nx4; j += stride) xb[j] = cvt4(x[j]);
  for (int j = i; j < nw4; j += stride) wqvg[j] = cvt4(wq[j]);
  for (int j = i; j < nw4; j += stride) wqvg[nw4 + j] = cvt4(wv[j]);
  for (int j = i; j < nw4; j += stride) wqvg[2 * nw4 + j] = cvt4(wg[j]);
  for (int j = i; j < nw4; j += stride) wob[j] = cvt4(wo[j]);
}

// ============ 256x256 tile, BK=64, 2-dbuf pipelined GEMM (frag-lead, r6) ============
// NO XCD swizzle (r8: broke L3 A-stream reuse, FETCH 2.7x — measured, reverted).
// + CARRY epilogue (r7): per-32-row-chunk EMA totals for v-columns from fp32 acc.

__device__ __forceinline__ void glds16(const u16* g, const u16* l) {
  __builtin_amdgcn_global_load_lds(
      (const __attribute__((address_space(1))) unsigned*)g,
      (__attribute__((address_space(3))) unsigned*)l, 16, 0, 0);
}

#define BAR() asm volatile("s_barrier" ::: "memory")
#define SB0() __builtin_amdgcn_sched_barrier(0)

template <typename OutT, bool CARRY>
__global__ __launch_bounds__(512, 2) void gemm256(const u16* __restrict__ X,
                                                  const u16* __restrict__ W,
                                                  OutT* __restrict__ Out,
                                                  float* __restrict__ carry,
                                                  const float* __restrict__ lamlog,
                                                  int M, int N, int K) {
  __shared__ u16 sm[8][8192];   // unit = d*4 + ab*2 + h ; 16 KB each
  const int tid = threadIdx.x;
  const int lane = tid & 63;
  const int wave = tid >> 6;              // 0..7
  const int ln15 = lane & 15, lh = lane >> 4;
  const int wr = wave >> 2, wc = wave & 3;
  const int bm = blockIdx.x * 256, bn = blockIdx.y * 256;
  const int NT = K >> 6;                  // K-tiles of 64 (>= 3)

  // ---- staging source (pre-swizzled global 16B-chunk within 128B row) ----
  const int srow = tid >> 3;                              // 0..63
  const int scol = ((tid & 7) ^ (srow & 7)) << 3;         // u16 col
  const u16* Asrc = X + (size_t)(bm + srow) * K + scol;
  const u16* Bsrc = W + (size_t)(bn + srow) * K + scol;
  const int ldsw = wave * 512;            // wave's u16 offset inside a unit

#define STAGE(u, h, tile, src)                                          \
  { const u16* _g = (src) + (size_t)((h) * 128) * K + (tile) * 64;      \
    glds16(_g,                  &sm[u][ldsw]);                          \
    glds16(_g + (size_t)64 * K, &sm[u][ldsw + 4096]); }

  // ---- ds_read bases (swizzled) ----
  const char* smb = (const char*)&sm[0][0];
  const char* Ard = smb + wr * 16384 + ln15 * 128;
  const char* Brd = smb + (2 + (wc >> 1)) * 16384 + ((wc & 1) * 64 + ln15) * 128;
  const int swz0 = ((lh ^ (ln15 & 7)) << 4);              // ks=0 chunk
  const int swz1 = (((4 + lh) ^ (ln15 & 7)) << 4);        // ks=1 chunk

#define RD_A(DB, MM, S) (*(const short8*)(Ard + (DB) + (MM) * 2048 + (S)))
#define RD_B(DB, NN, S) (*(const short8*)(Brd + (DB) + (NN) * 2048 + (S)))

  f32x4 acc[8][4];
  f32x4 zero = {0.f, 0.f, 0.f, 0.f};
  #pragma unroll
  for (int m = 0; m < 8; ++m)
    #pragma unroll
    for (int n = 0; n < 4; ++n) acc[m][n] = zero;

  short8 a[8][2], b[4][2];

#define MFMA_Q(M0, N0)                                                        \
  SB0();                                                                      \
  __builtin_amdgcn_s_setprio(1);                                              \
  _Pragma("unroll")                                                           \
  for (int m = (M0); m < (M0) + 4; ++m)                                       \
    _Pragma("unroll")                                                         \
    for (int n = (N0); n < (N0) + 2; ++n) {                                   \
      acc[m][n] = __builtin_amdgcn_mfma_f32_16x16x32_bf16(a[m][0], b[n][0], acc[m][n], 0, 0, 0); \
      acc[m][n] = __builtin_amdgcn_mfma_f32_16x16x32_bf16(a[m][1], b[n][1], acc[m][n], 0, 0, 0); \
    }                                                                         \
  __builtin_amdgcn_s_setprio(0);                                              \
  SB0();

  // ---- prologue ----
  STAGE(0, 0, 0, Asrc); STAGE(1, 1, 0, Asrc);
  STAGE(2, 0, 0, Bsrc); STAGE(3, 1, 0, Bsrc);
  STAGE(4, 0, 1, Asrc); STAGE(5, 1, 1, Asrc);
  asm volatile("s_waitcnt vmcnt(4)" ::: "memory");   // tile0 landed; A(1) flying
  BAR();
  #pragma unroll
  for (int m = 0; m < 4; ++m) { a[m][0] = RD_A(0, m, swz0); a[m][1] = RD_A(0, m, swz1); }
  #pragma unroll
  for (int n = 0; n < 4; ++n) { b[n][0] = RD_B(0, n, swz0); b[n][1] = RD_B(0, n, swz1); }

  for (int t = 0; t < NT; ++t) {
    const int d = t & 1;
    const int db = d * 65536;
    const int odb = (d ^ 1) * 65536;
    const int od = (d ^ 1) * 4;
    const int sd = d * 4;
    const int tB = (t + 1 < NT) ? t + 1 : NT - 1;
    const int tA = (t + 2 < NT) ? t + 2 : NT - 1;

    // ---- ph1: read a45(t); stage Bh0(t+1); MFMA Q1 = A0 x B0 ----
    a[4][0] = RD_A(db, 4, swz0); a[4][1] = RD_A(db, 4, swz1);
    a[5][0] = RD_A(db, 5, swz0); a[5][1] = RD_A(db, 5, swz1);
    STAGE(od + 2, 0, tB, Bsrc);
    MFMA_Q(0, 0)

    // ---- ph2: read a67(t); stage Bh1(t+1); MFMA Q2 = A0 x B1 ----
    a[6][0] = RD_A(db, 6, swz0); a[6][1] = RD_A(db, 6, swz1);
    a[7][0] = RD_A(db, 7, swz0); a[7][1] = RD_A(db, 7, swz1);
    STAGE(od + 3, 1, tB, Bsrc);
    MFMA_Q(0, 2)
    asm volatile("s_waitcnt vmcnt(4)" ::: "memory");
    BAR();

    // ---- ph3: read a03(t+1); MFMA Q3 = A1 x B1; stage Ah0(t+2) ----
    #pragma unroll
    for (int m = 0; m < 4; ++m) { a[m][0] = RD_A(odb, m, swz0); a[m][1] = RD_A(odb, m, swz1); }
    MFMA_Q(4, 2)
    STAGE(sd + 0, 0, tA, Asrc);
    asm volatile("s_waitcnt vmcnt(2)" ::: "memory");   // B(t+1) landed; Ah0(t+2) flying
    BAR();

    // ---- ph4: read b23(t+1); MFMA Q4 = A1 x B0; read b01(t+1); stage Ah1(t+2) ----
    b[2][0] = RD_B(odb, 2, swz0); b[2][1] = RD_B(odb, 2, swz1);
    b[3][0] = RD_B(odb, 3, swz0); b[3][1] = RD_B(odb, 3, swz1);
    MFMA_Q(4, 0)
    b[0][0] = RD_B(odb, 0, swz0); b[0][1] = RD_B(odb, 0, swz1);
    b[1][0] = RD_B(odb, 1, swz0); b[1][1] = RD_B(odb, 1, swz1);
    STAGE(sd + 1, 1, tA, Asrc);
  }
#undef STAGE
#undef RD_A
#undef RD_B
#undef MFMA_Q

  // ---- epilogue: C write ----
  #pragma unroll
  for (int m = 0; m < 8; ++m)
    #pragma unroll
    for (int n = 0; n < 4; ++n)
      #pragma unroll
      for (int r = 0; r < 4; ++r) {
        int row = bm + wr * 128 + m * 16 + lh * 4 + r;   // C/D: row=(lane>>4)*4+reg
        int col = bn + wc * 64 + n * 16 + ln15;          //      col=lane&15
        float vv = acc[m][n][r];
        if constexpr (sizeof(OutT) == 2) Out[(size_t)row * N + col] = f2b(vv);
        else                             Out[(size_t)row * N + col] = vv;
      }

  // ---- epilogue 2: per-chunk EMA totals for v-columns ----
  if constexpr (CARRY) {
    if (bn >= 1024 && bn < 2048) {
      const int bidx = bm >> 12;                         // batch (4096 rows each)
      const int chunkbase = ((bm & 4095) >> 5) + wr * 4; // 32-row chunks
      const int colbase = (bn - 1024) + wc * 64;         // v-col base (head-uniform)
      const float l2h = lamlog[colbase >> 6];
      float wgt[2][4];
      #pragma unroll
      for (int mo = 0; mo < 2; ++mo)
        #pragma unroll
        for (int r = 0; r < 4; ++r)
          wgt[mo][r] = exp2f(l2h * (float)(31 - (mo * 16 + lh * 4 + r)));
      #pragma unroll
      for (int mq = 0; mq < 4; ++mq) {      // chunk = chunkbase + mq
        #pragma unroll
        for (int n = 0; n < 4; ++n) {
          float part = 0.f;
          #pragma unroll
          for (int mo = 0; mo < 2; ++mo)
            #pragma unroll
            for (int r = 0; r < 4; ++r)
              part += wgt[mo][r] * acc[mq * 2 + mo][n][r];
          part += __shfl_down(part, 16);
          part += __shfl_down(part, 32);
          if (lh == 0)
            carry[(size_t)(bidx * NCH + chunkbase + mq) * D_MODEL +
                  colbase + n * 16 + ln15] = part;
        }
      }
    }
  }
}

// ---------------- carry prefix: c_j = lambda^CHUNK * c_{j-1} + total_j ----------------
__global__ void scan_carry(float* __restrict__ carry, const float* __restrict__ lam,
                           int B, int nch) {
  int idx = blockIdx.x * blockDim.x + threadIdx.x;
  if (idx >= B * D_MODEL) return;
  int b = idx >> 10, col = idx & (D_MODEL - 1);
  float lC = exp2f(lam[NHEAD + (col >> 6)] * (float)CHUNK);
  float c = 0.f;
  #pragma unroll 4
  for (int j = 0; j < nch; ++j) {
    size_t a = ((size_t)(b * nch + j)) * D_MODEL + col;
    c = lC * c + carry[a];
    carry[a] = c;
  }
}

// ---------------- fused local-scan + q*state + LayerNorm + SiLU gate ----------------
// r6 shape (256 thr, ushort4, one block per (b,chunk)) + 2-ROW iterations:
// 6 independent loads in flight (vs 3), 16 barriers/block (vs 32); two row
// reduces share one __syncthreads via parity slots.
__global__ __launch_bounds__(256) void scan_ln(const u16* __restrict__ qvg,
    const float* __restrict__ carry, const float* __restrict__ lam,
    const float* __restrict__ gamma, const float* __restrict__ lbeta,
    u16* __restrict__ yout, int S, int nch, int ld) {
  const int bj = blockIdx.x;               // b*nch + j
  const int b = bj / nch, j = bj - b * nch;
  const int tid = threadIdx.x;
  const int col0 = tid * 4;
  const float l = lam[col0 >> 6];
  const float l2 = l * l;
  const float4 gmv = *(const float4*)(gamma + col0);
  const float4 btv = *(const float4*)(lbeta + col0);
  const float gm[4] = {gmv.x, gmv.y, gmv.z, gmv.w};
  const float bt[4] = {btv.x, btv.y, btv.z, btv.w};

  float cp[4] = {0.f, 0.f, 0.f, 0.f};
  if (j > 0) {
    const float4 c4 = *(const float4*)(carry + (size_t)(bj - 1) * D_MODEL + col0);
    cp[0] = c4.x; cp[1] = c4.y; cp[2] = c4.z; cp[3] = c4.w;
  }
  float s[4] = {0.f, 0.f, 0.f, 0.f};
  float p = l;                              // lambda^{t+1} for row t
  const size_t row0 = (size_t)b * S + (size_t)j * CHUNK;
  const u16* base = qvg + row0 * ld + col0;

  ushort4 qu0 = *(const ushort4*)(base);
  ushort4 vu0 = *(const ushort4*)(base + D_MODEL);
  ushort4 gu0 = *(const ushort4*)(base + 2 * D_MODEL);
  ushort4 qu1 = *(const ushort4*)(base + ld);
  ushort4 vu1 = *(const ushort4*)(base + ld + D_MODEL);
  ushort4 gu1 = *(const ushort4*)(base + ld + 2 * D_MODEL);

  __shared__ float red[2][2][2][4];        // [parity][row][{sum,sq}][wave]
  const int ln = tid & 63, wv = tid >> 6;

  for (int t = 0; t < CHUNK; t += 2) {
    ushort4 qn0, vn0, gn0, qn1, vn1, gn1;
    if (t + 2 < CHUNK) {                   // prefetch rows t+2, t+3
      const u16* nb = base + (size_t)(t + 2) * ld;
      qn0 = *(const ushort4*)(nb);
      vn0 = *(const ushort4*)(nb + D_MODEL);
      gn0 = *(const ushort4*)(nb + 2 * D_MODEL);
      qn1 = *(const ushort4*)(nb + ld);
      vn1 = *(const ushort4*)(nb + ld + D_MODEL);
      gn1 = *(const ushort4*)(nb + ld + 2 * D_MODEL);
    }
    const float pt0 = p, pt1 = p * l;
    float q0[4], v0[4], q1[4], v1[4], y0[4], y1[4];
    u4f(qu0, q0); u4f(vu0, v0); u4f(qu1, q1); u4f(vu1, v1);
    float sum0 = 0.f, sq0 = 0.f, sum1 = 0.f, sq1 = 0.f;
    #pragma unroll
    for (int i = 0; i < 4; ++i) {
      s[i] = l * s[i] + v0[i];
      float st = s[i] + pt0 * cp[i];
      y0[i] = q0[i] * st; sum0 += y0[i]; sq0 += y0[i] * y0[i];
      s[i] = l * s[i] + v1[i];
      st = s[i] + pt1 * cp[i];
      y1[i] = q1[i] * st; sum1 += y1[i]; sq1 += y1[i] * y1[i];
    }
    #pragma unroll
    for (int off = 32; off > 0; off >>= 1) {
      sum0 += __shfl_down(sum0, off); sq0 += __shfl_down(sq0, off);
      sum1 += __shfl_down(sum1, off); sq1 += __shfl_down(sq1, off);
    }
    const int par = (t >> 1) & 1;
    if (ln == 0) {
      red[par][0][0][wv] = sum0; red[par][0][1][wv] = sq0;
      red[par][1][0][wv] = sum1; red[par][1][1][wv] = sq1;
    }
    __syncthreads();
    sum0 = red[par][0][0][0] + red[par][0][0][1] + red[par][0][0][2] + red[par][0][0][3];
    sq0  = red[par][0][1][0] + red[par][0][1][1] + red[par][0][1][2] + red[par][0][1][3];
    sum1 = red[par][1][0][0] + red[par][1][0][1] + red[par][1][0][2] + red[par][1][0][3];
    sq1  = red[par][1][1][0] + red[par][1][1][1] + red[par][1][1][2] + red[par][1][1][3];
    float mu0 = sum0 * (1.f / 1024.f);
    float rstd0 = rsqrtf(sq0 * (1.f / 1024.f) - mu0 * mu0 + LN_EPS);
    float mu1 = sum1 * (1.f / 1024.f);
    float rstd1 = rsqrtf(sq1 * (1.f / 1024.f) - mu1 * mu1 + LN_EPS);

    float g0[4], g1[4];
    u4f(gu0, g0); u4f(gu1, g1);
    ushort4 o0, o1;
    u16 ow0[4], ow1[4];
    #pragma unroll
    for (int i = 0; i < 4; ++i) {
      float gate0 = g0[i] / (1.f + __expf(-g0[i]));
      float gate1 = g1[i] / (1.f + __expf(-g1[i]));
      ow0[i] = f2b(((y0[i] - mu0) * rstd0 * gm[i] + bt[i]) * gate0);
      ow1[i] = f2b(((y1[i] - mu1) * rstd1 * gm[i] + bt[i]) * gate1);
    }
    o0.x = ow0[0]; o0.y = ow0[1]; o0.z = ow0[2]; o0.w = ow0[3];
    o1.x = ow1[0]; o1.y = ow1[1]; o1.z = ow1[2]; o1.w = ow1[3];
    *(ushort4*)(yout + (row0 + t) * D_MODEL + col0) = o0;
    *(ushort4*)(yout + (row0 + t + 1) * D_MODEL + col0) = o1;

    if (t + 2 < CHUNK) {
      qu0 = qn0; vu0 = vn0; gu0 = gn0;
      qu1 = qn1; vu1 = vn1; gu1 = gn1;
    }
    p *= l2;
  }
}

extern "C" void kernel_launch(void* const* d_in, const int* in_sizes, int n_in,
                              void* d_out, int out_size, void* d_ws, size_t ws_size,
                              hipStream_t stream) {
  const float* x     = (const float*)d_in[0];
  const float* Wq    = (const float*)d_in[1];
  const float* Wv    = (const float*)d_in[2];
  const float* Wo    = (const float*)d_in[3];
  const float* Wg    = (const float*)d_in[4];
  const float* beta  = (const float*)d_in[5];
  const float* gamma = (const float*)d_in[6];
  const float* lbeta = (const float*)d_in[7];
  float* out = (float*)d_out;

  const int BS = in_sizes[0] / D_MODEL;     // 16384
  const int S = S_LEN;                       // 4096
  const int B = BS / S;                      // 4
  const int nch = NCH;                       // 128
  const size_t nx = (size_t)BS * D_MODEL;
  const size_t nw = (size_t)D_MODEL * D_MODEL;
  const int N3 = 3 * D_MODEL;                // 3072

  char* w = (char*)d_ws;
  u16* xb   = (u16*)w;  w += nx * 2;
  u16* wqvg = (u16*)w;  w += 3 * nw * 2;     // packed [Wq;Wv;Wg] rows
  u16* wob  = (u16*)w;  w += nw * 2;
  u16* qvg  = (u16*)w;  w += (size_t)BS * N3 * 2;   // packed [q|v|g] per row
  u16* yb   = (u16*)w;  w += nx * 2;
  float* carry = (float*)w;  w += (size_t)B * nch * D_MODEL * 4;
  float* lam = (float*)w;

  cvt_all<<<2048, 256, 0, stream>>>((const float4*)x, (const float4*)Wq,
      (const float4*)Wv, (const float4*)Wg, (const float4*)Wo,
      (ushort4*)xb, (ushort4*)wqvg, (ushort4*)wob, beta, lam,
      (int)(nx / 4), (int)(nw / 4));

  dim3 g1(BS / 256, N3 / 256);      // 64 x 12
  gemm256<u16, true><<<g1, 512, 0, stream>>>(xb, wqvg, qvg, carry, lam + NHEAD,
                                             BS, N3, D_MODEL);

  scan_carry<<<(B * D_MODEL + 255) / 256, 256, 0, stream>>>(carry, lam, B, nch);
  scan_ln<<<B * nch, 256, 0, stream>>>(qvg, carry, lam, gamma, lbeta, yb, S, nch, N3);

  dim3 g2(BS / 256, D_MODEL / 256); // 64 x 4
  gemm256<float, false><<<g2, 512, 0, stream>>>(yb, wob, out, nullptr, nullptr,
                                                BS, D_MODEL, D_MODEL);
}

// Round 11
// 222.752 us; speedup vs baseline: 1.1119x; 1.0241x over previous
//
#include <hip/hip_runtime.h>

#define D_MODEL 1024
#define NHEAD 16
#define LN_EPS 1e-5f
#define CHUNK 32
#define S_LEN 4096
#define NCH (S_LEN / CHUNK)   // 128

typedef unsigned short u16;
typedef __attribute__((ext_vector_type(8))) short short8;
typedef __attribute__((ext_vector_type(4))) float f32x4;

__device__ __forceinline__ u16 f2b(float f) {
  unsigned u = __builtin_bit_cast(unsigned, f);
  u += 0x7FFFu + ((u >> 16) & 1u);   // RNE
  return (u16)(u >> 16);
}
__device__ __forceinline__ float b2f(u16 s) {
  return __builtin_bit_cast(float, ((unsigned)s) << 16);
}

// ---------------- fused fp32->bf16 convert (x + 4 weights) + lam ----------------
__device__ __forceinline__ ushort4 cvt4(float4 f) {
  ushort4 o; o.x = f2b(f.x); o.y = f2b(f.y); o.z = f2b(f.z); o.w = f2b(f.w);
  return o;
}
__global__ __launch_bounds__(256) void cvt_all(
    const float4* __restrict__ x,  const float4* __restrict__ wq,
    const float4* __restrict__ wv, const float4* __restrict__ wg,
    const float4* __restrict__ wo, ushort4* __restrict__ xb,
    ushort4* __restrict__ wqvg, ushort4* __restrict__ wob,
    const float* __restrict__ beta, float* __restrict__ lam,
    int nx4, int nw4) {
  int i = blockIdx.x * blockDim.x + threadIdx.x;
  int stride = gridDim.x * blockDim.x;
  if (blockIdx.x == 0 && threadIdx.x < NHEAD) {
    float l = 1.f / (1.f + __expf(-beta[threadIdx.x]));
    lam[threadIdx.x] = l;                  // lambda
    lam[NHEAD + threadIdx.x] = __log2f(l); // log2(lambda)
  }
  for (int j = i; j < nx4; j += stride) xb[j] = cvt4(x[j]);
  for (int j = i; j < nw4; j += stride) wqvg[j] = cvt4(wq[j]);
  for (int j = i; j < nw4; j += stride) wqvg[nw4 + j] = cvt4(wv[j]);
  for (int j = i; j < nw4; j += stride) wqvg[2 * nw4 + j] = cvt4(wg[j]);
  for (int j = i; j < nw4; j += stride) wob[j] = cvt4(wo[j]);
}

// ============ 256x256 tile, BK=64, 2-dbuf pipelined GEMM (frag-lead, r6) ============
// NO XCD swizzle (r8: broke L3 A-stream reuse, FETCH 2.7x — measured, reverted).
// + SCAN epilogue (r11): for v-column blocks, transform each 32-row chunk's fp32
// accumulators IN-REGISTER into the intra-chunk EMA prefix s_t = sum_{u<=t}
// lam^{t-u} v_u (3-level scan: in-lane r, cross-lh shfl_up x2, cross-half
// broadcast), then the generic C-write stores s (bf16) to the v-slot and the
// row-31 lanes (lh==3) store chunk totals to carry. Downstream scan becomes
// fully row-parallel (ew_ln) — no serial 32-row loop anywhere.

__device__ __forceinline__ void glds16(const u16* g, const u16* l) {
  __builtin_amdgcn_global_load_lds(
      (const __attribute__((address_space(1))) unsigned*)g,
      (__attribute__((address_space(3))) unsigned*)l, 16, 0, 0);
}

#define BAR() asm volatile("s_barrier" ::: "memory")
#define SB0() __builtin_amdgcn_sched_barrier(0)

template <typename OutT, bool CARRY>
__global__ __launch_bounds__(512, 2) void gemm256(const u16* __restrict__ X,
                                                  const u16* __restrict__ W,
                                                  OutT* __restrict__ Out,
                                                  float* __restrict__ carry,
                                                  const float* __restrict__ lamlog,
                                                  int M, int N, int K) {
  __shared__ u16 sm[8][8192];   // unit = d*4 + ab*2 + h ; 16 KB each
  const int tid = threadIdx.x;
  const int lane = tid & 63;
  const int wave = tid >> 6;              // 0..7
  const int ln15 = lane & 15, lh = lane >> 4;
  const int wr = wave >> 2, wc = wave & 3;
  const int bm = blockIdx.x * 256, bn = blockIdx.y * 256;
  const int NT = K >> 6;                  // K-tiles of 64 (>= 3)

  // ---- staging source (pre-swizzled global 16B-chunk within 128B row) ----
  const int srow = tid >> 3;                              // 0..63
  const int scol = ((tid & 7) ^ (srow & 7)) << 3;         // u16 col
  const u16* Asrc = X + (size_t)(bm + srow) * K + scol;
  const u16* Bsrc = W + (size_t)(bn + srow) * K + scol;
  const int ldsw = wave * 512;            // wave's u16 offset inside a unit

#define STAGE(u, h, tile, src)                                          \
  { const u16* _g = (src) + (size_t)((h) * 128) * K + (tile) * 64;      \
    glds16(_g,                  &sm[u][ldsw]);                          \
    glds16(_g + (size_t)64 * K, &sm[u][ldsw + 4096]); }

  // ---- ds_read bases (swizzled) ----
  const char* smb = (const char*)&sm[0][0];
  const char* Ard = smb + wr * 16384 + ln15 * 128;
  const char* Brd = smb + (2 + (wc >> 1)) * 16384 + ((wc & 1) * 64 + ln15) * 128;
  const int swz0 = ((lh ^ (ln15 & 7)) << 4);              // ks=0 chunk
  const int swz1 = (((4 + lh) ^ (ln15 & 7)) << 4);        // ks=1 chunk

#define RD_A(DB, MM, S) (*(const short8*)(Ard + (DB) + (MM) * 2048 + (S)))
#define RD_B(DB, NN, S) (*(const short8*)(Brd + (DB) + (NN) * 2048 + (S)))

  f32x4 acc[8][4];
  f32x4 zero = {0.f, 0.f, 0.f, 0.f};
  #pragma unroll
  for (int m = 0; m < 8; ++m)
    #pragma unroll
    for (int n = 0; n < 4; ++n) acc[m][n] = zero;

  short8 a[8][2], b[4][2];

#define MFMA_Q(M0, N0)                                                        \
  SB0();                                                                      \
  __builtin_amdgcn_s_setprio(1);                                              \
  _Pragma("unroll")                                                           \
  for (int m = (M0); m < (M0) + 4; ++m)                                       \
    _Pragma("unroll")                                                         \
    for (int n = (N0); n < (N0) + 2; ++n) {                                   \
      acc[m][n] = __builtin_amdgcn_mfma_f32_16x16x32_bf16(a[m][0], b[n][0], acc[m][n], 0, 0, 0); \
      acc[m][n] = __builtin_amdgcn_mfma_f32_16x16x32_bf16(a[m][1], b[n][1], acc[m][n], 0, 0, 0); \
    }                                                                         \
  __builtin_amdgcn_s_setprio(0);                                              \
  SB0();

  // ---- prologue ----
  STAGE(0, 0, 0, Asrc); STAGE(1, 1, 0, Asrc);
  STAGE(2, 0, 0, Bsrc); STAGE(3, 1, 0, Bsrc);
  STAGE(4, 0, 1, Asrc); STAGE(5, 1, 1, Asrc);
  asm volatile("s_waitcnt vmcnt(4)" ::: "memory");   // tile0 landed; A(1) flying
  BAR();
  #pragma unroll
  for (int m = 0; m < 4; ++m) { a[m][0] = RD_A(0, m, swz0); a[m][1] = RD_A(0, m, swz1); }
  #pragma unroll
  for (int n = 0; n < 4; ++n) { b[n][0] = RD_B(0, n, swz0); b[n][1] = RD_B(0, n, swz1); }

  for (int t = 0; t < NT; ++t) {
    const int d = t & 1;
    const int db = d * 65536;
    const int odb = (d ^ 1) * 65536;
    const int od = (d ^ 1) * 4;
    const int sd = d * 4;
    const int tB = (t + 1 < NT) ? t + 1 : NT - 1;
    const int tA = (t + 2 < NT) ? t + 2 : NT - 1;

    // ---- ph1: read a45(t); stage Bh0(t+1); MFMA Q1 = A0 x B0 ----
    a[4][0] = RD_A(db, 4, swz0); a[4][1] = RD_A(db, 4, swz1);
    a[5][0] = RD_A(db, 5, swz0); a[5][1] = RD_A(db, 5, swz1);
    STAGE(od + 2, 0, tB, Bsrc);
    MFMA_Q(0, 0)

    // ---- ph2: read a67(t); stage Bh1(t+1); MFMA Q2 = A0 x B1 ----
    a[6][0] = RD_A(db, 6, swz0); a[6][1] = RD_A(db, 6, swz1);
    a[7][0] = RD_A(db, 7, swz0); a[7][1] = RD_A(db, 7, swz1);
    STAGE(od + 3, 1, tB, Bsrc);
    MFMA_Q(0, 2)
    asm volatile("s_waitcnt vmcnt(4)" ::: "memory");
    BAR();

    // ---- ph3: read a03(t+1); MFMA Q3 = A1 x B1; stage Ah0(t+2) ----
    #pragma unroll
    for (int m = 0; m < 4; ++m) { a[m][0] = RD_A(odb, m, swz0); a[m][1] = RD_A(odb, m, swz1); }
    MFMA_Q(4, 2)
    STAGE(sd + 0, 0, tA, Asrc);
    asm volatile("s_waitcnt vmcnt(2)" ::: "memory");   // B(t+1) landed; Ah0(t+2) flying
    BAR();

    // ---- ph4: read b23(t+1); MFMA Q4 = A1 x B0; read b01(t+1); stage Ah1(t+2) ----
    b[2][0] = RD_B(odb, 2, swz0); b[2][1] = RD_B(odb, 2, swz1);
    b[3][0] = RD_B(odb, 3, swz0); b[3][1] = RD_B(odb, 3, swz1);
    MFMA_Q(4, 0)
    b[0][0] = RD_B(odb, 0, swz0); b[0][1] = RD_B(odb, 0, swz1);
    b[1][0] = RD_B(odb, 1, swz0); b[1][1] = RD_B(odb, 1, swz1);
    STAGE(sd + 1, 1, tA, Asrc);
  }
#undef STAGE
#undef RD_A
#undef RD_B
#undef MFMA_Q

  // ---- epilogue 0 (CARRY, v-columns): in-register intra-chunk EMA prefix ----
  // Chunk q rows (within wave): m=2q holds rows lh*4+r, m=2q+1 rows 16+lh*4+r.
  // 3-level scan; weights: row t gets lam^{t-u} from row u.
  if constexpr (CARRY) {
    if (bn >= 1024 && bn < 2048) {
      const float l2h = lamlog[((bn - 1024) + wc * 64) >> 6];
      const float lp1 = exp2f(l2h);
      const float lp2 = lp1 * lp1, lp3 = lp2 * lp1, lp4 = lp2 * lp2;
      const float l8 = lp4 * lp4;
      const float lpl = exp2f(l2h * (float)(4 * lh));   // lam^{4*lh}
      #pragma unroll
      for (int q = 0; q < 4; ++q)
        #pragma unroll
        for (int n = 0; n < 4; ++n) {
          f32x4 A0 = acc[2 * q][n], A1 = acc[2 * q + 1][n];
          // in-lane prefix over r (4 contiguous rows)
          A0[1] += lp1 * A0[0]; A0[2] += lp1 * A0[1]; A0[3] += lp1 * A0[2];
          A1[1] += lp1 * A1[0]; A1[2] += lp1 * A1[1]; A1[3] += lp1 * A1[2];
          // cross-lh scan (4 groups of 4 rows), ratio lam^4
          float S = A0[3], x;
          x = __shfl_up(S, 16); if (lh >= 1) S += lp4 * x;
          x = __shfl_up(S, 32); if (lh >= 2) S += l8 * x;
          float Xc = __shfl_up(S, 16); Xc = (lh >= 1) ? Xc : 0.f;  // S_{g-1}
          A0[0] += lp1 * Xc; A0[1] += lp2 * Xc; A0[2] += lp3 * Xc; A0[3] += lp4 * Xc;
          // full prefix through row 15 (lh=3, r=3 of first half)
          float f15 = __shfl(A0[3], 48 + ln15);
          // second half: same cross-lh scan + cross-half carry
          S = A1[3];
          x = __shfl_up(S, 16); if (lh >= 1) S += lp4 * x;
          x = __shfl_up(S, 32); if (lh >= 2) S += l8 * x;
          Xc = __shfl_up(S, 16); Xc = (lh >= 1) ? Xc : 0.f;
          Xc += lpl * f15;   // row 16+lh*4+r gets lam^{lh*4+r+1} * f15
          A1[0] += lp1 * Xc; A1[1] += lp2 * Xc; A1[2] += lp3 * Xc; A1[3] += lp4 * Xc;
          acc[2 * q][n] = A0; acc[2 * q + 1][n] = A1;
        }
    }
  }

  // ---- epilogue 1: C write (v-blocks now hold the local prefix s) ----
  #pragma unroll
  for (int m = 0; m < 8; ++m)
    #pragma unroll
    for (int n = 0; n < 4; ++n)
      #pragma unroll
      for (int r = 0; r < 4; ++r) {
        int row = bm + wr * 128 + m * 16 + lh * 4 + r;   // C/D: row=(lane>>4)*4+reg
        int col = bn + wc * 64 + n * 16 + ln15;          //      col=lane&15
        float vv = acc[m][n][r];
        if constexpr (sizeof(OutT) == 2) Out[(size_t)row * N + col] = f2b(vv);
        else                             Out[(size_t)row * N + col] = vv;
      }

  // ---- epilogue 2: chunk totals = prefix at row 31 (lh==3, r==3, odd half) ----
  if constexpr (CARRY) {
    if (bn >= 1024 && bn < 2048 && lh == 3) {
      const int bidx = bm >> 12;                         // batch (4096 rows each)
      const int chunkbase = ((bm & 4095) >> 5) + wr * 4; // 32-row chunks
      const int colbase = (bn - 1024) + wc * 64;         // v-col base
      #pragma unroll
      for (int q = 0; q < 4; ++q)
        #pragma unroll
        for (int n = 0; n < 4; ++n)
          carry[(size_t)(bidx * NCH + chunkbase + q) * D_MODEL +
                colbase + n * 16 + ln15] = acc[2 * q + 1][n][3];
    }
  }
}

// ---------------- carry prefix: c_j = lambda^CHUNK * c_{j-1} + total_j ----------------
__global__ void scan_carry(float* __restrict__ carry, const float* __restrict__ lam,
                           int B, int nch) {
  int idx = blockIdx.x * blockDim.x + threadIdx.x;
  if (idx >= B * D_MODEL) return;
  int b = idx >> 10, col = idx & (D_MODEL - 1);
  float lC = exp2f(lam[NHEAD + (col >> 6)] * (float)CHUNK);
  float c = 0.f;
  #pragma unroll 4
  for (int j = 0; j < nch; ++j) {
    size_t a = ((size_t)(b * nch + j)) * D_MODEL + col;
    c = lC * c + carry[a];
    carry[a] = c;
  }
}

// ---------------- row-parallel q*state + LayerNorm + SiLU gate ----------------
// One block per row; v-slot of qvg already holds the intra-chunk prefix s_t,
// so st = s_t + lam^{tl+1} * carry[j-1] — no serial dependence anywhere.
__global__ __launch_bounds__(256) void ew_ln(const u16* __restrict__ qvg,
    const float* __restrict__ carry, const float* __restrict__ lam,
    const float* __restrict__ gamma, const float* __restrict__ lbeta,
    u16* __restrict__ yout, int nch, int ld) {
  int row = blockIdx.x;
  int b = row >> 12;                      // S = 4096
  int srow = row & 4095;
  int j = srow >> 5, tl = srow & 31;      // CHUNK = 32
  int tid = threadIdx.x;
  int col0 = tid * 4;
  size_t rb = (size_t)row * ld;

  ushort4 qu = *(const ushort4*)(qvg + rb + col0);
  ushort4 su = *(const ushort4*)(qvg + rb + D_MODEL + col0);
  float st[4] = {b2f(su.x), b2f(su.y), b2f(su.z), b2f(su.w)};
  if (j > 0) {
    float p = exp2f(lam[NHEAD + (col0 >> 6)] * (float)(tl + 1));
    const float4 c4 = *(const float4*)(carry + ((size_t)(b * nch + j - 1)) * D_MODEL + col0);
    st[0] += p * c4.x; st[1] += p * c4.y; st[2] += p * c4.z; st[3] += p * c4.w;
  }
  float q[4] = {b2f(qu.x), b2f(qu.y), b2f(qu.z), b2f(qu.w)};
  float y[4];
  float sum = 0.f, sumsq = 0.f;
  #pragma unroll
  for (int i = 0; i < 4; ++i) {
    y[i] = q[i] * st[i];
    sum += y[i];
    sumsq += y[i] * y[i];
  }
  #pragma unroll
  for (int off = 32; off > 0; off >>= 1) {
    sum += __shfl_down(sum, off);
    sumsq += __shfl_down(sumsq, off);
  }
  __shared__ float red[8];
  int ln = tid & 63, wv = tid >> 6;
  if (ln == 0) { red[wv] = sum; red[4 + wv] = sumsq; }
  __syncthreads();
  sum = red[0] + red[1] + red[2] + red[3];
  sumsq = red[4] + red[5] + red[6] + red[7];
  float mu = sum * (1.f / 1024.f);
  float var = sumsq * (1.f / 1024.f) - mu * mu;
  float rstd = rsqrtf(var + LN_EPS);

  float4 gm = *(const float4*)(gamma + col0);
  float4 bt = *(const float4*)(lbeta + col0);
  ushort4 gu = *(const ushort4*)(qvg + rb + 2 * D_MODEL + col0);
  float gv[4]  = {b2f(gu.x), b2f(gu.y), b2f(gu.z), b2f(gu.w)};
  float gmv[4] = {gm.x, gm.y, gm.z, gm.w};
  float btv[4] = {bt.x, bt.y, bt.z, bt.w};
  u16 ov[4];
  #pragma unroll
  for (int i = 0; i < 4; ++i) {
    float gate = gv[i] / (1.f + __expf(-gv[i]));   // SiLU
    float oo = ((y[i] - mu) * rstd * gmv[i] + btv[i]) * gate;
    ov[i] = f2b(oo);
  }
  ushort4 o; o.x = ov[0]; o.y = ov[1]; o.z = ov[2]; o.w = ov[3];
  *(ushort4*)(yout + (size_t)row * D_MODEL + col0) = o;
}

extern "C" void kernel_launch(void* const* d_in, const int* in_sizes, int n_in,
                              void* d_out, int out_size, void* d_ws, size_t ws_size,
                              hipStream_t stream) {
  const float* x     = (const float*)d_in[0];
  const float* Wq    = (const float*)d_in[1];
  const float* Wv    = (const float*)d_in[2];
  const float* Wo    = (const float*)d_in[3];
  const float* Wg    = (const float*)d_in[4];
  const float* beta  = (const float*)d_in[5];
  const float* gamma = (const float*)d_in[6];
  const float* lbeta = (const float*)d_in[7];
  float* out = (float*)d_out;

  const int BS = in_sizes[0] / D_MODEL;     // 16384
  const int B = BS / S_LEN;                  // 4
  const int nch = NCH;                       // 128
  const size_t nx = (size_t)BS * D_MODEL;
  const size_t nw = (size_t)D_MODEL * D_MODEL;
  const int N3 = 3 * D_MODEL;                // 3072

  char* w = (char*)d_ws;
  u16* xb   = (u16*)w;  w += nx * 2;
  u16* wqvg = (u16*)w;  w += 3 * nw * 2;     // packed [Wq;Wv;Wg] rows
  u16* wob  = (u16*)w;  w += nw * 2;
  u16* qvg  = (u16*)w;  w += (size_t)BS * N3 * 2;   // packed [q|s|g] per row
  u16* yb   = (u16*)w;  w += nx * 2;
  float* carry = (float*)w;  w += (size_t)B * nch * D_MODEL * 4;
  float* lam = (float*)w;

  cvt_all<<<2048, 256, 0, stream>>>((const float4*)x, (const float4*)Wq,
      (const float4*)Wv, (const float4*)Wg, (const float4*)Wo,
      (ushort4*)xb, (ushort4*)wqvg, (ushort4*)wob, beta, lam,
      (int)(nx / 4), (int)(nw / 4));

  dim3 g1(BS / 256, N3 / 256);      // 64 x 12
  gemm256<u16, true><<<g1, 512, 0, stream>>>(xb, wqvg, qvg, carry, lam + NHEAD,
                                             BS, N3, D_MODEL);

  scan_carry<<<(B * D_MODEL + 255) / 256, 256, 0, stream>>>(carry, lam, B, nch);
  ew_ln<<<BS, 256, 0, stream>>>(qvg, carry, lam, gamma, lbeta, yb, nch, N3);

  dim3 g2(BS / 256, D_MODEL / 256); // 64 x 4
  gemm256<float, false><<<g2, 512, 0, stream>>>(yb, wob, out, nullptr, nullptr,
                                                BS, D_MODEL, D_MODEL);
}